// Round 8
// baseline (148.271 us; speedup 1.0000x reference)
//
#include <hip/hip_runtime.h>

// Problem constants
#define BB 16
#define TT 2000
#define DD 512
#define OO 41              // real output classes
#define CN 11
#define KTOT (CN * DD)     // 5632
#define MT 256             // time steps per block (4 waves x 64 rows)
#define ROWS (MT + CN - 1) // 266 feature rows staged
#define HALF 256           // D-split half width (split-K over D)
#define NIT 88             // K-iters per split: 11 frames x 8 chunks of 32
#define NTHREADS 256       // 4 waves

typedef short short8 __attribute__((ext_vector_type(8)));
typedef float f32x4 __attribute__((ext_vector_type(4)));

__device__ __forceinline__ ushort f2bf(float f) {
    unsigned u = __builtin_bit_cast(unsigned, f);
    u += 0x7FFFu + ((u >> 16) & 1u);   // RNE; inputs are finite normals
    return (ushort)(u >> 16);
}

// Relayout W (41x5632 f32) into MFMA-fragment-major bf16, split-aware:
// chunk c = (split*88 + i)*3 + nblk ; ushort offset = c*512 + lane*8
// value = W[nblk*16 + (lane&15)][ (i>>3)*512 + split*256 + (i&7)*32 + (lane>>4)*8 + e ]
__global__ void prep_w_kernel(const float* __restrict__ W, ushort* __restrict__ Wf) {
    int tid = blockIdx.x * 256 + threadIdx.x;
    if (tid >= 176 * 3 * 64) return;
    int lane = tid & 63;
    int c    = tid >> 6;          // 0..527
    int nblk = c % 3;
    int itg  = c / 3;             // 0..175 = split*88 + i
    int split = itg / NIT;
    int i     = itg % NIT;
    int j    = i >> 3;
    int dcq  = i & 7;
    int row  = nblk * 16 + (lane & 15);
    int col  = j * DD + split * HALF + dcq * 32 + (lane >> 4) * 8;
    short8 h = short8{0,0,0,0,0,0,0,0};
    if (row < OO) {
        const float* p = W + (size_t)row * KTOT + col;
        #pragma unroll
        for (int e = 0; e < 8; ++e) h[e] = (short)f2bf(p[e]);
    }
    *(short8*)(Wf + (size_t)tid * 8) = h;
}

__global__ __launch_bounds__(NTHREADS, 1)
void conv_gemm_kernel(const float* __restrict__ F,
                      const ushort* __restrict__ Wfrag,
                      const float* __restrict__ bias,
                      float* __restrict__ out) {
    __shared__ ushort ldsA[ROWS * HALF];   // 136192 B -> 1 block/CU

    const int tid   = threadIdx.x;
    const int b     = blockIdx.y;
    const int t0    = blockIdx.x * MT;
    const int split = blockIdx.z;
    const float* Fb = F + (size_t)b * TT * DD + split * HALF;
    const int wave = tid >> 6;
    const int lane = tid & 63;
    const int lrow = lane & 15;
    const int lk   = lane >> 4;

    const ushort* wp0 = Wfrag + (size_t)(split * NIT) * 1536 + lane * 8;

    short8 bs[4][3];   // 4-deep B ring (static indices only)
    short8 aa[2][4];   // 2-deep A parity ping-pong x 4 M-tiles
    f32x4 acc[4][3];

    // ---- B prologue: slots 0..3 issued BEFORE staging (latency hidden) ----
    #pragma unroll
    for (int p = 0; p < 4; ++p) {
        #pragma unroll
        for (int n = 0; n < 3; ++n)
            bs[p][n] = *(const short8*)(wp0 + p * 1536 + n * 512);
    }

    // ---- Stage 266 half-rows (clipped) as bf16 into LDS, XOR-swizzled ----
    for (int i = tid; i < ROWS * (HALF / 4); i += NTHREADS) {
        int row = i >> 6;          // 64 float4 per half-row
        int c4  = i & 63;
        int t = t0 + row - 5;
        t = t < 0 ? 0 : (t > TT - 1 ? TT - 1 : t);
        float4 v = *(const float4*)(Fb + (size_t)t * DD + c4 * 4);
        ushort4 h;
        h.x = f2bf(v.x); h.y = f2bf(v.y); h.z = f2bf(v.z); h.w = f2bf(v.w);
        int base = row * 512 + c4 * 8;   // bytes; half-row pitch = 512 B
        *(ushort4*)((char*)ldsA + (base ^ ((row & 7) << 4))) = h;
    }
    __syncthreads();

    const int am = wave * 64 + lrow + 10;   // A row = am + m*16 - j

    // A-frag fetch from LDS (swizzled); g = K-iter, m = M-tile
    auto LDA = [&](int g, int m) -> short8 {
        int r = am + m * 16 - (g >> 3);
        int byteoff = r * 512 + (((g & 7) * 32 + lk * 8) << 1);
        return *(const short8*)((const char*)ldsA + (byteoff ^ ((r & 7) << 4)));
    };

    #pragma unroll
    for (int m = 0; m < 4; ++m) {
        aa[0][m] = LDA(0, m);
        aa[1][m] = LDA(1, m);
        #pragma unroll
        for (int n = 0; n < 3; ++n) acc[m][n] = f32x4{0.f, 0.f, 0.f, 0.f};
    }

    // Sub-iteration macro: position p (literal), parity e=p&1.
    // Consumes bs[p], aa[e]; optionally refills bs[p] (g+4) and aa[e] (g+2).
#define SUBITER(p, PREF_B, PREF_A)                                             \
    {                                                                          \
        constexpr int e_ = (p) & 1;                                            \
        _Pragma("unroll")                                                      \
        for (int m = 0; m < 4; ++m) {                                          \
            acc[m][0] = __builtin_amdgcn_mfma_f32_16x16x32_bf16(aa[e_][m], bs[p][0], acc[m][0], 0, 0, 0); \
            acc[m][1] = __builtin_amdgcn_mfma_f32_16x16x32_bf16(aa[e_][m], bs[p][1], acc[m][1], 0, 0, 0); \
            acc[m][2] = __builtin_amdgcn_mfma_f32_16x16x32_bf16(aa[e_][m], bs[p][2], acc[m][2], 0, 0, 0); \
        }                                                                      \
        if (PREF_B) {                                                          \
            const ushort* q_ = wpb + ((p) + 4) * 1536;                         \
            bs[p][0] = *(const short8*)(q_);                                   \
            bs[p][1] = *(const short8*)(q_ + 512);                             \
            bs[p][2] = *(const short8*)(q_ + 1024);                           \
        }                                                                      \
        if (PREF_A) {                                                          \
            const int g2_ = gb + (p) + 2;                                      \
            _Pragma("unroll")                                                  \
            for (int m = 0; m < 4; ++m) aa[e_][m] = LDA(g2_, m);               \
        }                                                                      \
    }

    // ---- Main loop: 21 outer iters (g = 0..83), full prefetch ----
    const ushort* wpb = wp0;
    int gb = 0;
    for (; gb < NIT - 4; gb += 4) {
        SUBITER(0, true, true)
        SUBITER(1, true, true)
        SUBITER(2, true, true)
        SUBITER(3, true, true)
        wpb += 4 * 1536;
    }
    // ---- Peeled final 4 sub-iters (g = 84..87): no B-prefetch ----
    SUBITER(0, false, true)    // prefetches A for g=86
    SUBITER(1, false, true)    // prefetches A for g=87
    SUBITER(2, false, false)
    SUBITER(3, false, false)
#undef SUBITER

    // ---- Epilogue: C[row=lk*4+q][col], atomicAdd partials; split 0 adds bias ----
    const float bias0 = (split == 0) ? bias[lrow] : 0.f;
    const float bias1 = (split == 0) ? bias[16 + lrow] : 0.f;
    const float bias2 = (split == 0 && 32 + lrow < OO) ? bias[32 + lrow] : 0.f;
    float* outb = out + (size_t)b * TT * OO;
    #pragma unroll
    for (int m = 0; m < 4; ++m) {
        const int tbase = t0 + wave * 64 + m * 16 + lk * 4;
        #pragma unroll
        for (int q = 0; q < 4; ++q) {
            const int t = tbase + q;
            if (t < TT) {
                float* po = outb + (size_t)t * OO;
                atomicAdd(po + lrow,      acc[m][0][q] + bias0);
                atomicAdd(po + 16 + lrow, acc[m][1][q] + bias1);
                if (32 + lrow < OO) atomicAdd(po + 32 + lrow, acc[m][2][q] + bias2);
            }
        }
    }
}

extern "C" void kernel_launch(void* const* d_in, const int* in_sizes, int n_in,
                              void* d_out, int out_size, void* d_ws, size_t ws_size,
                              hipStream_t stream) {
    const float* F    = (const float*)d_in[0];
    const float* W    = (const float*)d_in[1];
    const float* bias = (const float*)d_in[2];
    float* out = (float*)d_out;

    ushort* Wb = (ushort*)d_ws;                 // 540672 B needed
    const int prep_threads = 176 * 3 * 64;      // 33792
    prep_w_kernel<<<(prep_threads + 255) / 256, 256, 0, stream>>>(W, Wb);

    const dim3 grid((TT + MT - 1) / MT, BB, 2);   // 8 x 16 x 2 = 256 blocks
    conv_gemm_kernel<<<grid, NTHREADS, 0, stream>>>(F, Wb, bias, out);
}

// Round 9
// 141.820 us; speedup vs baseline: 1.0455x; 1.0455x over previous
//
#include <hip/hip_runtime.h>

// Problem constants
#define BB 16
#define TT 2000
#define DD 512
#define OO 41              // real output classes
#define CN 11
#define KTOT (CN * DD)     // 5632
#define MT 64              // time steps per block (4 waves x 16 rows)
#define ROWS (MT + CN - 1) // 74 feature rows staged
#define HALF 128           // D-split width (4-way split-K over D)
#define NSPLIT 4
#define NIT 44             // K-iters per split: 11 frames x 4 chunks of 32
#define NTHREADS 256       // 4 waves

typedef short short8 __attribute__((ext_vector_type(8)));
typedef float f32x4 __attribute__((ext_vector_type(4)));

__device__ __forceinline__ ushort f2bf(float f) {
    unsigned u = __builtin_bit_cast(unsigned, f);
    u += 0x7FFFu + ((u >> 16) & 1u);   // RNE; inputs are finite normals
    return (ushort)(u >> 16);
}

// Relayout W (41x5632 f32) into MFMA-fragment-major bf16, 4-split-aware:
// global chunk c = (split*44 + i)*3 + nblk ; ushort offset = c*512 + lane*8
// value = W[nblk*16 + (lane&15)][ (i>>2)*512 + split*128 + (i&3)*32 + (lane>>4)*8 + e ]
__global__ void prep_w_kernel(const float* __restrict__ W, ushort* __restrict__ Wf) {
    int tid = blockIdx.x * 256 + threadIdx.x;
    if (tid >= 176 * 3 * 64) return;
    int lane = tid & 63;
    int c    = tid >> 6;          // 0..527
    int nblk = c % 3;
    int itg  = c / 3;             // 0..175 = split*44 + i
    int split = itg / NIT;
    int i     = itg % NIT;
    int j    = i >> 2;
    int dcq  = i & 3;
    int row  = nblk * 16 + (lane & 15);
    int col  = j * DD + split * HALF + dcq * 32 + (lane >> 4) * 8;
    short8 h = short8{0,0,0,0,0,0,0,0};
    if (row < OO) {
        const float* p = W + (size_t)row * KTOT + col;
        #pragma unroll
        for (int e = 0; e < 8; ++e) h[e] = (short)f2bf(p[e]);
    }
    *(short8*)(Wf + (size_t)tid * 8) = h;
}

__global__ __launch_bounds__(NTHREADS, 8)
void conv_gemm_kernel(const float* __restrict__ F,
                      const ushort* __restrict__ Wfrag,
                      const float* __restrict__ bias,
                      float* __restrict__ out) {
    __shared__ ushort ldsA[ROWS * HALF];   // 18944 B -> 8 blocks/CU

    const int tid   = threadIdx.x;
    const int b     = blockIdx.y;
    const int t0    = blockIdx.x * MT;
    const int split = blockIdx.z;
    const float* Fb = F + (size_t)b * TT * DD + split * HALF;

    // ---- Stage 74 quarter-rows (clipped) as bf16 into LDS, XOR-swizzled ----
    for (int i = tid; i < ROWS * (HALF / 4); i += NTHREADS) {
        int row = i >> 5;          // 32 float4 per quarter-row
        int c4  = i & 31;
        int t = t0 + row - 5;
        t = t < 0 ? 0 : (t > TT - 1 ? TT - 1 : t);
        float4 v = *(const float4*)(Fb + (size_t)t * DD + c4 * 4);
        ushort4 h;
        h.x = f2bf(v.x); h.y = f2bf(v.y); h.z = f2bf(v.z); h.w = f2bf(v.w);
        int base = row * 256 + c4 * 8;   // bytes; quarter-row pitch = 256 B
        *(ushort4*)((char*)ldsA + (base ^ ((row & 7) << 4))) = h;
    }
    __syncthreads();

    const int wave = tid >> 6;
    const int lane = tid & 63;
    const int lrow = lane & 15;
    const int lk   = lane >> 4;
    const int am   = wave * 16 + lrow + 10;   // A row = am - j

    // A-frag fetch from LDS (swizzled); g = K-iter within split
    auto LDA = [&](int g) -> short8 {
        int r = am - (g >> 2);
        int byteoff = r * 256 + (((g & 3) * 32 + lk * 8) << 1);
        return *(const short8*)((const char*)ldsA + (byteoff ^ ((r & 7) << 4)));
    };

    const ushort* wp = Wfrag + (size_t)(split * NIT) * 1536 + lane * 8;

    f32x4 acc0 = {0.f, 0.f, 0.f, 0.f};
    f32x4 acc1 = {0.f, 0.f, 0.f, 0.f};
    f32x4 acc2 = {0.f, 0.f, 0.f, 0.f};

    // ---- 2-deep register-pipelined K loop, no barriers (R7 structure) ----
    short8 a0 = LDA(0), a1 = LDA(1);
    short8 b00 = *(const short8*)(wp);
    short8 b01 = *(const short8*)(wp + 512);
    short8 b02 = *(const short8*)(wp + 1024);
    short8 b10 = *(const short8*)(wp + 1536);
    short8 b11 = *(const short8*)(wp + 2048);
    short8 b12 = *(const short8*)(wp + 2560);

    for (int i = 0; i < NIT; i += 2) {
        acc0 = __builtin_amdgcn_mfma_f32_16x16x32_bf16(a0, b00, acc0, 0, 0, 0);
        acc1 = __builtin_amdgcn_mfma_f32_16x16x32_bf16(a0, b01, acc1, 0, 0, 0);
        acc2 = __builtin_amdgcn_mfma_f32_16x16x32_bf16(a0, b02, acc2, 0, 0, 0);
        if (i + 2 < NIT) {
            const ushort* q = wp + 2 * 1536;
            a0  = LDA(i + 2);
            b00 = *(const short8*)(q);
            b01 = *(const short8*)(q + 512);
            b02 = *(const short8*)(q + 1024);
        }
        acc0 = __builtin_amdgcn_mfma_f32_16x16x32_bf16(a1, b10, acc0, 0, 0, 0);
        acc1 = __builtin_amdgcn_mfma_f32_16x16x32_bf16(a1, b11, acc1, 0, 0, 0);
        acc2 = __builtin_amdgcn_mfma_f32_16x16x32_bf16(a1, b12, acc2, 0, 0, 0);
        if (i + 3 < NIT) {
            const ushort* q = wp + 3 * 1536;
            a1  = LDA(i + 3);
            b10 = *(const short8*)(q);
            b11 = *(const short8*)(q + 512);
            b12 = *(const short8*)(q + 1024);
        }
        wp += 2 * 1536;
    }

    // ---- Epilogue: C[row=lk*4+q][col], atomicAdd partials; split 0 adds bias ----
    const float bias0 = (split == 0) ? bias[lrow] : 0.f;
    const float bias1 = (split == 0) ? bias[16 + lrow] : 0.f;
    const float bias2 = (split == 0 && 32 + lrow < OO) ? bias[32 + lrow] : 0.f;
    const int tbase = t0 + wave * 16 + lk * 4;
    float* outb = out + (size_t)b * TT * OO;
    #pragma unroll
    for (int q = 0; q < 4; ++q) {
        const int t = tbase + q;
        if (t < TT) {
            float* po = outb + (size_t)t * OO;
            atomicAdd(po + lrow,      acc0[q] + bias0);
            atomicAdd(po + 16 + lrow, acc1[q] + bias1);
            if (32 + lrow < OO) atomicAdd(po + 32 + lrow, acc2[q] + bias2);
        }
    }
}

extern "C" void kernel_launch(void* const* d_in, const int* in_sizes, int n_in,
                              void* d_out, int out_size, void* d_ws, size_t ws_size,
                              hipStream_t stream) {
    const float* F    = (const float*)d_in[0];
    const float* W    = (const float*)d_in[1];
    const float* bias = (const float*)d_in[2];
    float* out = (float*)d_out;

    ushort* Wb = (ushort*)d_ws;                 // 540672 B needed
    const int prep_threads = 176 * 3 * 64;      // 33792
    prep_w_kernel<<<(prep_threads + 255) / 256, 256, 0, stream>>>(W, Wb);

    const dim3 grid((TT + MT - 1) / MT, BB, NSPLIT);   // 32 x 16 x 4 = 2048 blocks
    conv_gemm_kernel<<<grid, NTHREADS, 0, stream>>>(F, Wb, bias, out);
}

// Round 11
// 135.215 us; speedup vs baseline: 1.0966x; 1.0488x over previous
//
#include <hip/hip_runtime.h>

// Problem constants
#define BB 16
#define TT 2000
#define DD 512
#define OO 41              // real output classes
#define CN 11
#define KTOT (CN * DD)     // 5632
#define MT 256             // time steps per block (8 waves x 32 rows)
#define ROWS (MT + CN - 1) // 266 feature rows staged
#define HALF 128           // D-split width (4-way split-K over D)
#define NSPLIT 4
#define NIT 44             // K-triplets per split: 11 frames x 4 chunks of 32
#define NROUND (NIT / 2)   // 22 rounds x 2 triplets
#define NTHREADS 512       // 8 waves

typedef short short8 __attribute__((ext_vector_type(8)));
typedef float f32x4 __attribute__((ext_vector_type(4)));

__device__ __forceinline__ ushort f2bf(float f) {
    unsigned u = __builtin_bit_cast(unsigned, f);
    u += 0x7FFFu + ((u >> 16) & 1u);   // RNE; inputs are finite normals
    return (ushort)(u >> 16);
}

// async global->LDS, 16B per lane.
// NOTE: global source address is PER-LANE (must include lane*16B);
// LDS dest is wave-uniform base + lane*16 (hardware-applied).
__device__ __forceinline__ void gll16(const ushort* gsrc, ushort* ldst) {
    auto* g = (const __attribute__((address_space(1))) unsigned int*)(gsrc);
    auto* l = (__attribute__((address_space(3))) unsigned int*)(ldst);
    __builtin_amdgcn_global_load_lds(g, l, 16, 0, 0);
}

// Relayout W (41x5632 f32) into MFMA-fragment-major bf16, 4-split-aware:
// global chunk c = (split*44 + i)*3 + nblk ; ushort offset = c*512 + lane*8
// value = W[nblk*16 + (lane&15)][ (i>>2)*512 + split*128 + (i&3)*32 + (lane>>4)*8 + e ]
__global__ void prep_w_kernel(const float* __restrict__ W, ushort* __restrict__ Wf) {
    int tid = blockIdx.x * 256 + threadIdx.x;
    if (tid >= 176 * 3 * 64) return;
    int lane = tid & 63;
    int c    = tid >> 6;          // 0..527
    int nblk = c % 3;
    int itg  = c / 3;             // 0..175 = split*44 + i
    int split = itg / NIT;
    int i     = itg % NIT;
    int j    = i >> 2;
    int dcq  = i & 3;
    int row  = nblk * 16 + (lane & 15);
    int col  = j * DD + split * HALF + dcq * 32 + (lane >> 4) * 8;
    short8 h = short8{0,0,0,0,0,0,0,0};
    if (row < OO) {
        const float* p = W + (size_t)row * KTOT + col;
        #pragma unroll
        for (int e = 0; e < 8; ++e) h[e] = (short)f2bf(p[e]);
    }
    *(short8*)(Wf + (size_t)tid * 8) = h;
}

__global__ __launch_bounds__(NTHREADS, 4)
void conv_gemm_kernel(const float* __restrict__ F,
                      const ushort* __restrict__ Wfrag,
                      const float* __restrict__ bias,
                      float* __restrict__ out) {
    __shared__ ushort ldsA[ROWS * HALF];     // 68096 B, XOR-swizzled
    __shared__ ushort ldsB[2 * 3072];        // 12288 B: 2 bufs x 2 triplets x 3 chunks x 512

    const int tid   = threadIdx.x;
    const int b     = blockIdx.y;
    const int t0    = blockIdx.x * MT;
    const int split = blockIdx.z;
    const float* Fb = F + (size_t)b * TT * DD + split * HALF;
    const int wave = tid >> 6;
    const int lane = tid & 63;

    // this split's stream; lane*8 ushorts = the per-lane 16B the HW expects
    const ushort* Wsp = Wfrag + (size_t)split * NIT * 1536 + lane * 8;

    // ---- Prologue: issue round-0 B stage (6 chunks; waves 0..5, one each) ----
    if (wave < 6) gll16(Wsp + wave * 512, ldsB + wave * 512);

    // ---- Stage 266 quarter-rows (clipped) as bf16 into LDS, XOR-swizzled ----
    for (int i = tid; i < ROWS * (HALF / 4); i += NTHREADS) {
        int row = i >> 5;          // 32 float4 per quarter-row
        int c4  = i & 31;
        int t = t0 + row - 5;
        t = t < 0 ? 0 : (t > TT - 1 ? TT - 1 : t);
        float4 v = *(const float4*)(Fb + (size_t)t * DD + c4 * 4);
        ushort4 h;
        h.x = f2bf(v.x); h.y = f2bf(v.y); h.z = f2bf(v.z); h.w = f2bf(v.w);
        int base = row * 256 + c4 * 8;   // bytes; quarter-row pitch = 256 B
        *(ushort4*)((char*)ldsA + (base ^ ((row & 7) << 4))) = h;
    }
    __syncthreads();   // A visible; round-0 B loads also drained by the full waitcnt

    const int lrow = lane & 15;
    const int lk   = lane >> 4;
    const int am   = wave * 32 + lrow + 10;   // A row = am + m*16 - j

    // A-frag fetch from LDS (swizzled); g = K-triplet index, m = M-tile
    auto LDA = [&](int g, int m) -> short8 {
        int r = am + m * 16 - (g >> 2);
        int byteoff = r * 256 + (((g & 3) * 32 + lk * 8) << 1);
        return *(const short8*)((const char*)ldsA + (byteoff ^ ((r & 7) << 4)));
    };

    f32x4 acc[2][3];
    #pragma unroll
    for (int m = 0; m < 2; ++m)
        #pragma unroll
        for (int n = 0; n < 3; ++n) acc[m][n] = f32x4{0.f, 0.f, 0.f, 0.f};

    // ---- K loop: 22 rounds x 2 triplets; B double-buffered in LDS, counted vmcnt ----
    for (int r = 0; r < NROUND; ++r) {
        __builtin_amdgcn_s_barrier();        // everyone done reading buf[(r+1)&1]
        __builtin_amdgcn_sched_barrier(0);
        if (r + 1 < NROUND) {
            if (wave < 6)
                gll16(Wsp + (size_t)(r + 1) * 3072 + wave * 512,
                      ldsB + ((r + 1) & 1) * 3072 + wave * 512);
            asm volatile("s_waitcnt vmcnt(1)" ::: "memory");   // my round-r chunk done
        } else {
            asm volatile("s_waitcnt vmcnt(0)" ::: "memory");
        }
        __builtin_amdgcn_s_barrier();        // all 6 round-r chunks visible
        __builtin_amdgcn_sched_barrier(0);

        const ushort* bb = ldsB + (r & 1) * 3072;
        #pragma unroll
        for (int s = 0; s < 2; ++s) {
            const int g = 2 * r + s;
            short8 b0 = *(const short8*)(bb + s * 1536 + lane * 8);
            short8 b1 = *(const short8*)(bb + s * 1536 + 512 + lane * 8);
            short8 b2 = *(const short8*)(bb + s * 1536 + 1024 + lane * 8);
            #pragma unroll
            for (int m = 0; m < 2; ++m) {
                short8 a = LDA(g, m);
                acc[m][0] = __builtin_amdgcn_mfma_f32_16x16x32_bf16(a, b0, acc[m][0], 0, 0, 0);
                acc[m][1] = __builtin_amdgcn_mfma_f32_16x16x32_bf16(a, b1, acc[m][1], 0, 0, 0);
                acc[m][2] = __builtin_amdgcn_mfma_f32_16x16x32_bf16(a, b2, acc[m][2], 0, 0, 0);
            }
        }
    }

    // ---- Epilogue: C[row=lk*4+q][col], atomicAdd partials; split 0 adds bias ----
    const float bias0 = (split == 0) ? bias[lrow] : 0.f;
    const float bias1 = (split == 0) ? bias[16 + lrow] : 0.f;
    const float bias2 = (split == 0 && 32 + lrow < OO) ? bias[32 + lrow] : 0.f;
    float* outb = out + (size_t)b * TT * OO;
    #pragma unroll
    for (int m = 0; m < 2; ++m) {
        const int tbase = t0 + wave * 32 + m * 16 + lk * 4;
        #pragma unroll
        for (int q = 0; q < 4; ++q) {
            const int t = tbase + q;
            if (t < TT) {
                float* po = outb + (size_t)t * OO;
                atomicAdd(po + lrow,      acc[m][0][q] + bias0);
                atomicAdd(po + 16 + lrow, acc[m][1][q] + bias1);
                if (32 + lrow < OO) atomicAdd(po + 32 + lrow, acc[m][2][q] + bias2);
            }
        }
    }
}

extern "C" void kernel_launch(void* const* d_in, const int* in_sizes, int n_in,
                              void* d_out, int out_size, void* d_ws, size_t ws_size,
                              hipStream_t stream) {
    const float* F    = (const float*)d_in[0];
    const float* W    = (const float*)d_in[1];
    const float* bias = (const float*)d_in[2];
    float* out = (float*)d_out;

    ushort* Wb = (ushort*)d_ws;                 // 540672 B needed
    const int prep_threads = 176 * 3 * 64;      // 33792
    prep_w_kernel<<<(prep_threads + 255) / 256, 256, 0, stream>>>(W, Wb);

    const dim3 grid((TT + MT - 1) / MT, BB, NSPLIT);   // 8 x 16 x 4 = 512 blocks
    conv_gemm_kernel<<<grid, NTHREADS, 0, stream>>>(F, Wb, bias, out);
}